// Round 9
// baseline (211.050 us; speedup 1.0000x reference)
//
#include <hip/hip_runtime.h>
#include <stdint.h>

#define B_TOT 16384
#define F_NUM 24
#define P_NUM 276
#define BT    64          // b-rows per block (2 MFMA n-tiles sharing each W-frag)
#define NTH   768         // 12 waves -> 3 waves/SIMD; VGPR cap ~170
#define NWV   12
#define CHNK  23          // 276 = 12 * 23
#define ROWP2 776         // shorts per LDS row: 24*32 + 8 pad (1552 B = 4 dw mod 32)

typedef float f32x16 __attribute__((ext_vector_type(16)));
typedef float f32x4  __attribute__((ext_vector_type(4)));
typedef short bf16x8 __attribute__((ext_vector_type(8)));

__device__ inline unsigned short f2bf(float f) {
    unsigned u = __float_as_uint(f);
    u += 0x7fffu + ((u >> 16) & 1u);      // round-to-nearest-even
    return (unsigned short)(u >> 16);
}
__device__ inline float bf2f(unsigned short h) {
    return __uint_as_float(((unsigned)h) << 16);
}

// ---- pair schedule: 276 pairs (i-major) in 12 chunks of 23 -----------------
// entry = p | (j<<9) | (i<<14) | (flag<<19); flag at i-change or chunk end.
struct Tab { int ent[NWV][CHNK]; };
constexpr Tab build_tab() {
    Tab t{};
    int ii[276] = {}, jj[276] = {};
    int n = 0;
    for (int i = 0; i < 24; ++i)
        for (int j = i + 1; j < 24; ++j) { ii[n] = i; jj[n] = j; ++n; }
    int pos = 0;
    for (int w = 0; w < NWV; ++w) {
        for (int k = 0; k < CHNK; ++k, ++pos) {
            int flag = (k == CHNK - 1) || (ii[pos + 1] != ii[pos]);
            t.ent[w][k] = pos | (jj[pos] << 9) | (ii[pos] << 14) | (flag << 19);
        }
    }
    return t;
}
__device__ __constant__ Tab gtab = build_tab();

// ---- prepass: W fp32 -> bf16 A-fragments (unchanged layout) ----------------
// chunk(p, u) u=ks*2+m at afrag[((p*8+u)*64 + lane)*8]:
//   elem i = W[p][m*32 + (lane&31)][ks*16 + (lane>>5)*8 + i]
__global__ __launch_bounds__(256) void wprep(const float* __restrict__ W,
                                             unsigned short* __restrict__ afrag) {
    __shared__ __align__(16) unsigned short wlds[64 * 72];
    int p = blockIdx.x, t = threadIdx.x;
    const float4* src = (const float4*)(W + (size_t)p * 4096);
    #pragma unroll
    for (int c = 0; c < 4; ++c) {
        int i = t + c * 256;
        float4 v = src[i];
        int d = i >> 4;
        int e = (i & 15) * 4;
        ushort4 h; h.x=f2bf(v.x); h.y=f2bf(v.y); h.z=f2bf(v.z); h.w=f2bf(v.w);
        *(ushort4*)(&wlds[d * 72 + e]) = h;
    }
    __syncthreads();
    #pragma unroll
    for (int c = 0; c < 2; ++c) {
        int sl = t + c * 256;
        int u = sl >> 6, lane = sl & 63;
        int ks = u >> 1, m = u & 1;
        int d = m * 32 + (lane & 31);
        int e = ks * 16 + (lane >> 5) * 8;
        bf16x8 v = *(const bf16x8*)(&wlds[d * 72 + e]);
        *(bf16x8*)(afrag + ((size_t)(p * 8 + u) * 64 + lane) * 8) = v;
    }
}

#define MF(A_, B_, C_) __builtin_amdgcn_mfma_f32_32x32x16_bf16(A_, B_, C_, 0, 0, 0)

// 4 forced 16B loads, one base + offset: immediates; "=&v" early-clobber so
// dest tuples never alias the address (round-6 crash fix).
#define GLDW4(PB_, N0,N1,N2,N3) do {                                           \
    const bf16x8* pb_ = (PB_);                                                 \
    asm volatile(                                                              \
        "global_load_dwordx4 %0, %4, off\n\t"                                  \
        "global_load_dwordx4 %1, %4, off offset:1024\n\t"                      \
        "global_load_dwordx4 %2, %4, off offset:2048\n\t"                      \
        "global_load_dwordx4 %3, %4, off offset:3072"                          \
        : "=&v"(N0),"=&v"(N1),"=&v"(N2),"=&v"(N3) : "v"(pb_));                 \
} while (0)

// phase-partial epilogue (exact by linearity): V(d) half m==PH_ dotted with
// x_i from LDS (bf16, staged this phase); half m==1-PH_ from global fp32.
#define EPI(E_, PH_) do {                                                      \
    int fi_ = ((E_) >> 14) & 31;                                               \
    const unsigned short* p0_ = xr0 + fi_ * 32 + q4;                           \
    const unsigned short* p1_ = xr1 + fi_ * 32 + q4;                           \
    const float* g0_ = xg0 + fi_ * 64 + (1 - (PH_)) * 32 + q4;                 \
    const float* g1_ = xg1 + fi_ * 64 + (1 - (PH_)) * 32 + q4;                 \
    f32x16& L0_ = (PH_) ? a01 : a00;                                           \
    f32x16& L1_ = (PH_) ? a11 : a10;                                           \
    f32x16& G0_ = (PH_) ? a00 : a01;                                           \
    f32x16& G1_ = (PH_) ? a10 : a11;                                           \
    _Pragma("unroll")                                                          \
    for (int g_ = 0; g_ < 4; ++g_) {                                           \
        ushort4 u_ = *(const ushort4*)(p0_ + 8 * g_);                          \
        tacc0 += L0_[4*g_+0]*bf2f(u_.x) + L0_[4*g_+1]*bf2f(u_.y)               \
               + L0_[4*g_+2]*bf2f(u_.z) + L0_[4*g_+3]*bf2f(u_.w);              \
        u_ = *(const ushort4*)(p1_ + 8 * g_);                                  \
        tacc1 += L1_[4*g_+0]*bf2f(u_.x) + L1_[4*g_+1]*bf2f(u_.y)               \
               + L1_[4*g_+2]*bf2f(u_.z) + L1_[4*g_+3]*bf2f(u_.w);              \
        f32x4 v_ = *(const f32x4*)(g0_ + 8 * g_);                              \
        tacc0 += G0_[4*g_+0]*v_[0] + G0_[4*g_+1]*v_[1]                         \
               + G0_[4*g_+2]*v_[2] + G0_[4*g_+3]*v_[3];                        \
        v_ = *(const f32x4*)(g1_ + 8 * g_);                                    \
        tacc1 += G1_[4*g_+0]*v_[0] + G1_[4*g_+1]*v_[1]                         \
               + G1_[4*g_+2]*v_[2] + G1_[4*g_+3]*v_[3];                        \
    }                                                                          \
    _Pragma("unroll")                                                          \
    for (int k_ = 0; k_ < 16; ++k_) { a00[k_]=0.f; a01[k_]=0.f;                \
                                      a10[k_]=0.f; a11[k_]=0.f; }              \
} while (0)

// consume pair E_ (W frags C0..C3 = ksl{0,1}x m{0,1}; X frags nt{0,1}x ksl),
// prefetch pair NE_'s 4 W-frags + 4 x k-slices.  Counted vmcnt(4): the 4
// just-issued loads stay in flight across the 8 MFMAs.
#define PSTEP2(E_, NE_, PH_, C0,C1,C2,C3, X0,X1,X2,X3,                         \
                           N0,N1,N2,N3, Y0,Y1,Y2,Y3) do {                      \
    GLDW4(afr + ((size_t)((NE_) & 511) * 8 + 4 * (PH_)) * 64 + lane,           \
          N0,N1,N2,N3);                                                        \
    { int jo_ = (((NE_) >> 9) & 31) * 32;                                      \
      const unsigned short* b0_ = xr0 + jo_ + q8;                              \
      const unsigned short* b1_ = xr1 + jo_ + q8;                              \
      Y0 = *(const bf16x8*)(b0_);      Y1 = *(const bf16x8*)(b0_ + 16);        \
      Y2 = *(const bf16x8*)(b1_);      Y3 = *(const bf16x8*)(b1_ + 16); }      \
    asm volatile("s_waitcnt vmcnt(4)");                                        \
    __builtin_amdgcn_sched_barrier(0);                                         \
    __builtin_amdgcn_s_setprio(1);                                             \
    a00 = MF(C0, X0, a00); a10 = MF(C0, X2, a10);                              \
    a01 = MF(C1, X0, a01); a11 = MF(C1, X2, a11);                              \
    a00 = MF(C2, X1, a00); a10 = MF(C2, X3, a10);                              \
    a01 = MF(C3, X1, a01); a11 = MF(C3, X3, a11);                              \
    __builtin_amdgcn_s_setprio(0);                                             \
    if ((E_) & (1 << 19)) EPI(E_, PH_);                                        \
} while (0)

// tail: drain (vmcnt(0)) so nothing is in flight at phase end / s_endpgm.
#define PSTEP2_LAST(E_, PH_, C0,C1,C2,C3, X0,X1,X2,X3) do {                    \
    asm volatile("s_waitcnt vmcnt(0)");                                        \
    __builtin_amdgcn_sched_barrier(0);                                         \
    __builtin_amdgcn_s_setprio(1);                                             \
    a00 = MF(C0, X0, a00); a10 = MF(C0, X2, a10);                              \
    a01 = MF(C1, X0, a01); a11 = MF(C1, X2, a11);                              \
    a00 = MF(C2, X1, a00); a10 = MF(C2, X3, a10);                              \
    a01 = MF(C3, X1, a01); a11 = MF(C3, X3, a11);                              \
    __builtin_amdgcn_s_setprio(0);                                             \
    if ((E_) & (1 << 19)) EPI(E_, PH_);                                        \
} while (0)

// one e-half phase: W prologue (flies under stage) -> stage half-dims ->
// pair loop.  PH_ is a literal 0/1 so all selects fold at compile time.
#define PHASE_BODY(PH_) {                                                      \
    bf16x8 WA0,WA1,WA2,WA3, WB0,WB1,WB2,WB3;                                   \
    bf16x8 XA0,XA1,XA2,XA3, XB0,XB1,XB2,XB3;                                   \
    const int ef_ = gtab.ent[wv][0];                                           \
    GLDW4(afr + ((size_t)(ef_ & 511) * 8 + 4 * (PH_)) * 64 + lane,             \
          WA0,WA1,WA2,WA3);                                                    \
    if (PH_) __syncthreads();                                                  \
    _Pragma("unroll 4")                                                        \
    for (int c = 0; c < 16; ++c) {                                             \
        int idx = tid + c * NTH;        /* 64 rows x 24 f x 8 f4 = 12288 */    \
        int row = idx / 192;                                                   \
        int rem = idx - row * 192;                                             \
        int f   = rem >> 3;                                                    \
        int c4  = rem & 7;                                                     \
        f32x4 v = __builtin_nontemporal_load(                                  \
            (const f32x4*)(xg + (size_t)row * 1536 + f * 64 + (PH_) * 32       \
                           + c4 * 4));                                         \
        ushort4 h; h.x=f2bf(v[0]); h.y=f2bf(v[1]);                             \
                   h.z=f2bf(v[2]); h.w=f2bf(v[3]);                             \
        *(ushort4*)(&xs[row * ROWP2 + f * 32 + c4 * 4]) = h;                   \
    }                                                                          \
    __syncthreads();                                                           \
    { int jo = ((ef_ >> 9) & 31) * 32;                                         \
      const unsigned short* b0 = xr0 + jo + q8;                                \
      const unsigned short* b1 = xr1 + jo + q8;                                \
      XA0 = *(const bf16x8*)(b0);      XA1 = *(const bf16x8*)(b0 + 16);        \
      XA2 = *(const bf16x8*)(b1);      XA3 = *(const bf16x8*)(b1 + 16); }      \
    _Pragma("unroll 1")                                                        \
    for (int s = 0; s + 1 < CHNK; s += 2) {                                    \
        int e0 = gtab.ent[wv][s];                                              \
        int e1 = gtab.ent[wv][s + 1];                                          \
        int s2 = (s + 2 < CHNK) ? s + 2 : s + 1;                               \
        int e2 = gtab.ent[wv][s2];                                             \
        PSTEP2(e0, e1, PH_, WA0,WA1,WA2,WA3, XA0,XA1,XA2,XA3,                  \
                            WB0,WB1,WB2,WB3, XB0,XB1,XB2,XB3);                 \
        PSTEP2(e1, e2, PH_, WB0,WB1,WB2,WB3, XB0,XB1,XB2,XB3,                  \
                            WA0,WA1,WA2,WA3, XA0,XA1,XA2,XA3);                 \
    }                                                                          \
    { int el = gtab.ent[wv][CHNK - 1];                                         \
      PSTEP2_LAST(el, PH_, WA0,WA1,WA2,WA3, XA0,XA1,XA2,XA3); }                \
}

// ---- main kernel -----------------------------------------------------------
__global__ __launch_bounds__(NTH, 3) void fmfm_main(const float* __restrict__ x,
                                                    const unsigned short* __restrict__ afrag,
                                                    float* __restrict__ out) {
    __shared__ __align__(16) unsigned short xs[BT * ROWP2];   // 99,328 B
    __shared__ float t_red[BT];
    const int tid = threadIdx.x;
    const int btile = blockIdx.x;
    const int lane = tid & 63;
    const int wv = __builtin_amdgcn_readfirstlane(tid >> 6);   // 0..11
    const int bcol = lane & 31;
    const int q = lane >> 5;
    const int q8 = q * 8, q4 = q * 4;

    if (tid < BT) t_red[tid] = 0.0f;

    const bf16x8* afr = (const bf16x8*)afrag;
    const unsigned short* xr0 = xs + bcol * ROWP2;          // n-tile 0 row
    const unsigned short* xr1 = xs + (32 + bcol) * ROWP2;   // n-tile 1 row
    const float* xg  = x + (size_t)btile * BT * 1536;
    const float* xg0 = xg + (size_t)bcol * 1536;            // epilogue f32 rows
    const float* xg1 = xg0 + (size_t)32 * 1536;

    float tacc0 = 0.f, tacc1 = 0.f;
    f32x16 a00, a01, a10, a11;            // acc[ntile][m]
    #pragma unroll
    for (int k = 0; k < 16; ++k) { a00[k]=0.f; a01[k]=0.f; a10[k]=0.f; a11[k]=0.f; }

    PHASE_BODY(0)
    PHASE_BODY(1)

    atomicAdd(&t_red[bcol],      tacc0);
    atomicAdd(&t_red[32 + bcol], tacc1);
    __syncthreads();
    if (tid < BT) out[(size_t)btile * BT + tid] = t_red[tid];
}

extern "C" void kernel_launch(void* const* d_in, const int* in_sizes, int n_in,
                              void* d_out, int out_size, void* d_ws, size_t ws_size,
                              hipStream_t stream) {
    const float* x = (const float*)d_in[0];
    const float* W = (const float*)d_in[1];
    float* out = (float*)d_out;
    unsigned short* afrag = (unsigned short*)d_ws;   // 2.26 MB scratch
    wprep<<<P_NUM, 256, 0, stream>>>(W, afrag);
    fmfm_main<<<B_TOT / BT, NTH, 0, stream>>>(x, afrag, out);
}

// Round 13
// 183.760 us; speedup vs baseline: 1.1485x; 1.1485x over previous
//
#include <hip/hip_runtime.h>
#include <stdint.h>

#define B_TOT 16384
#define F_NUM 24
#define P_NUM 276
#define BT    32          // b-rows per block (1 MFMA n-tile)
#define NTH   512         // 8 waves -> 2 waves/SIMD; VGPR cap 256
#define NWV   8
#define ROWP  1544        // shorts per LDS row: 24*64 + 8 pad

typedef float f32x16 __attribute__((ext_vector_type(16)));
typedef float f32x4  __attribute__((ext_vector_type(4)));
typedef short bf16x8 __attribute__((ext_vector_type(8)));

__device__ inline unsigned short f2bf(float f) {
    unsigned u = __float_as_uint(f);
    u += 0x7fffu + ((u >> 16) & 1u);      // round-to-nearest-even
    return (unsigned short)(u >> 16);
}
__device__ inline float bf2f(unsigned short h) {
    return __uint_as_float(((unsigned)h) << 16);
}

// ---- pair schedule: 276 pairs (i-major) in 8 chunks {36 x2, 34 x6} ---------
// all chunk sizes EVEN -> clean 2-step ping-pong, no odd tail.
// entry = p | (j<<9) | (i<<14) | (flag<<19); flag at i-change or chunk end.
struct Tab { int ent[NWV][36]; int cnt[NWV]; };
constexpr Tab build_tab() {
    Tab t{};
    int ii[276] = {}, jj[276] = {};
    int n = 0;
    for (int i = 0; i < 24; ++i)
        for (int j = i + 1; j < 24; ++j) { ii[n] = i; jj[n] = j; ++n; }
    int pos = 0;
    for (int w = 0; w < NWV; ++w) {
        int c = (w < 2) ? 36 : 34;       // 2*36 + 6*34 = 276
        t.cnt[w] = c;
        for (int k = 0; k < c; ++k, ++pos) {
            int flag = (k == c - 1) || (ii[pos + 1] != ii[pos]);
            t.ent[w][k] = pos | (jj[pos] << 9) | (ii[pos] << 14) | (flag << 19);
        }
    }
    return t;
}
__device__ __constant__ Tab gtab = build_tab();

// ---- prepass: W fp32 -> bf16 A-fragments, pair-major chunk layout ----------
// chunk(p, u) u=ks*2+m at afrag[((p*8+u)*64 + lane)*8]:
//   elem i = W[p][m*32 + (lane&31)][ks*16 + (lane>>5)*8 + i]
__global__ __launch_bounds__(256) void wprep(const float* __restrict__ W,
                                             unsigned short* __restrict__ afrag) {
    __shared__ __align__(16) unsigned short wlds[64 * 72];
    int p = blockIdx.x, t = threadIdx.x;
    const float4* src = (const float4*)(W + (size_t)p * 4096);
    #pragma unroll
    for (int c = 0; c < 4; ++c) {
        int i = t + c * 256;
        float4 v = src[i];
        int d = i >> 4;
        int e = (i & 15) * 4;
        ushort4 h; h.x=f2bf(v.x); h.y=f2bf(v.y); h.z=f2bf(v.z); h.w=f2bf(v.w);
        *(ushort4*)(&wlds[d * 72 + e]) = h;
    }
    __syncthreads();
    #pragma unroll
    for (int c = 0; c < 2; ++c) {
        int sl = t + c * 256;
        int u = sl >> 6, lane = sl & 63;
        int ks = u >> 1, m = u & 1;
        int d = m * 32 + (lane & 31);
        int e = ks * 16 + (lane >> 5) * 8;
        bf16x8 v = *(const bf16x8*)(&wlds[d * 72 + e]);
        *(bf16x8*)(afrag + ((size_t)(p * 8 + u) * 64 + lane) * 8) = v;
    }
}

#define MF(A_, B_, C_) __builtin_amdgcn_mfma_f32_32x32x16_bf16(A_, B_, C_, 0, 0, 0)

// 8x forced 16B global loads in ONE asm block; "=&v" early-clobber (round-6
// lesson: async dest must never alias address regs).  Low-pressure use only
// (round-10 lesson: this pattern is fragile once the allocator must spill).
#define GLDW8(P_, N0,N1,N2,N3,N4,N5,N6,N7) do {                                \
    const bf16x8* b0_ = (P_);                                                  \
    const bf16x8* b1_ = (P_) + 256;                                            \
    asm volatile(                                                              \
        "global_load_dwordx4 %0, %8, off\n\t"                                  \
        "global_load_dwordx4 %1, %8, off offset:1024\n\t"                      \
        "global_load_dwordx4 %2, %8, off offset:2048\n\t"                      \
        "global_load_dwordx4 %3, %8, off offset:3072\n\t"                      \
        "global_load_dwordx4 %4, %9, off\n\t"                                  \
        "global_load_dwordx4 %5, %9, off offset:1024\n\t"                      \
        "global_load_dwordx4 %6, %9, off offset:2048\n\t"                      \
        "global_load_dwordx4 %7, %9, off offset:3072"                          \
        : "=&v"(N0),"=&v"(N1),"=&v"(N2),"=&v"(N3),                             \
          "=&v"(N4),"=&v"(N5),"=&v"(N6),"=&v"(N7)                              \
        : "v"(b0_), "v"(b1_));                                                 \
} while (0)

// epilogue: V = (a0+a2 | a1+a3) dotted with x_i from LDS; zero accs.
// Exact under partial flushes (out linear in V).  V[m][4g+j] at d=m*32+8g+4q+j
#define EPI(E_) do {                                                           \
    int fi_ = ((E_) >> 14) & 31;                                               \
    const unsigned short* ep_ = xrow + fi_ * 64 + q4;                          \
    _Pragma("unroll")                                                          \
    for (int g_ = 0; g_ < 4; ++g_) {                                           \
        ushort4 u_ = *(const ushort4*)(ep_ + 8 * g_);                          \
        tacc += (a0[4*g_+0]+a2[4*g_+0])*bf2f(u_.x)                             \
              + (a0[4*g_+1]+a2[4*g_+1])*bf2f(u_.y)                             \
              + (a0[4*g_+2]+a2[4*g_+2])*bf2f(u_.z)                             \
              + (a0[4*g_+3]+a2[4*g_+3])*bf2f(u_.w);                            \
        u_ = *(const ushort4*)(ep_ + 32 + 8 * g_);                             \
        tacc += (a1[4*g_+0]+a3[4*g_+0])*bf2f(u_.x)                             \
              + (a1[4*g_+1]+a3[4*g_+1])*bf2f(u_.y)                             \
              + (a1[4*g_+2]+a3[4*g_+2])*bf2f(u_.z)                             \
              + (a1[4*g_+3]+a3[4*g_+3])*bf2f(u_.w);                            \
    }                                                                          \
    _Pragma("unroll")                                                          \
    for (int k_ = 0; k_ < 16; ++k_) { a0[k_]=0.f; a1[k_]=0.f;                  \
                                      a2[k_]=0.f; a3[k_]=0.f; }                \
} while (0)

// PSTEP: consume pair E_ from {C*,X*}, prefetch pair NE_ into {N*,Y*}.
// 8 MFMAs over FOUR independent chains (a0..a3, depth 2 each; dep distance
// 4 instrs ~ 128 cyc) instead of two depth-4 chains — the round-10 theory:
// MFMA dep-chain latency, not byte supply, sets the ~1160-cyc slot time.
// Counted vmcnt(8): the 8 just-issued next-pair loads stay in flight.
#define PSTEP(E_, NE_, C0,C1,C2,C3,C4,C5,C6,C7, X0,X1,X2,X3,                   \
                        N0,N1,N2,N3,N4,N5,N6,N7, Y0,Y1,Y2,Y3) do {             \
    GLDW8(afr + (size_t)((NE_) & 511) * 512 + lane,                            \
          N0,N1,N2,N3,N4,N5,N6,N7);                                            \
    { const unsigned short* bp_ = xrow + (((NE_) >> 9) & 31) * 64 + q8;        \
      Y0 = *(const bf16x8*)(bp_);      Y1 = *(const bf16x8*)(bp_ + 16);        \
      Y2 = *(const bf16x8*)(bp_ + 32); Y3 = *(const bf16x8*)(bp_ + 48); }      \
    asm volatile("s_waitcnt vmcnt(8)");                                        \
    __builtin_amdgcn_sched_barrier(0);                                         \
    __builtin_amdgcn_s_setprio(1);                                             \
    a0 = MF(C0, X0, a0);   /* m0, ks0 */                                       \
    a1 = MF(C1, X0, a1);   /* m1, ks0 */                                       \
    a2 = MF(C4, X2, a2);   /* m0, ks2 */                                       \
    a3 = MF(C5, X2, a3);   /* m1, ks2 */                                       \
    a0 = MF(C2, X1, a0);   /* m0, ks1 */                                       \
    a1 = MF(C3, X1, a1);   /* m1, ks1 */                                       \
    a2 = MF(C6, X3, a2);   /* m0, ks3 */                                       \
    a3 = MF(C7, X3, a3);   /* m1, ks3 */                                       \
    __builtin_amdgcn_s_setprio(0);                                             \
    if ((E_) & (1 << 19)) EPI(E_);                                             \
} while (0)

// ---- main kernel -----------------------------------------------------------
__global__ __launch_bounds__(NTH, 2) void fmfm_main(const float* __restrict__ x,
                                                    const unsigned short* __restrict__ afrag,
                                                    float* __restrict__ out) {
    __shared__ __align__(16) unsigned short xs[BT * ROWP];   // 98,816 B
    __shared__ float t_red[BT];
    const int tid = threadIdx.x;
    const int btile = blockIdx.x;
    const int lane = tid & 63;
    const int wv = __builtin_amdgcn_readfirstlane(tid >> 6);   // 0..7
    const int bcol = lane & 31;
    const int q = lane >> 5;
    const int q8 = q * 8, q4 = q * 4;

    if (tid < BT) t_red[tid] = 0.0f;

    const bf16x8* afr = (const bf16x8*)afrag;
    const unsigned short* xrow = xs + bcol * ROWP;

    float tacc = 0.f;
    f32x16 a0, a1, a2, a3;                // acc[chain]: m x ks-half
    #pragma unroll
    for (int k = 0; k < 16; ++k) { a0[k]=0.f; a1[k]=0.f; a2[k]=0.f; a3[k]=0.f; }

    bf16x8 WA0,WA1,WA2,WA3,WA4,WA5,WA6,WA7;   // W buffer, ping
    bf16x8 WB0,WB1,WB2,WB3,WB4,WB5,WB6,WB7;   // W buffer, pong
    bf16x8 XA0,XA1,XA2,XA3;                   // x k-slice buffers, ping
    bf16x8 XB0,XB1,XB2,XB3;                   // x k-slice buffers, pong

    const int cnt = gtab.cnt[wv];
    const int ef  = gtab.ent[wv][0];
    // prefetch pair0's W BEFORE staging: 8 loads fly under the whole stage
    GLDW8(afr + (size_t)(ef & 511) * 512 + lane,
          WA0,WA1,WA2,WA3,WA4,WA5,WA6,WA7);

    // stage full tile: 32 rows x 6KB fp32 -> bf16 LDS, contiguous NT reads
    const float* xg = x + (size_t)btile * BT * 1536;
    #pragma unroll 4
    for (int c = 0; c < 24; ++c) {
        int idx = tid + c * NTH;         // 0..12287 float4 index
        int row = idx / 384;
        int c4  = idx - row * 384;
        f32x4 v = __builtin_nontemporal_load(
                      (const f32x4*)(xg + (size_t)row * 1536 + c4 * 4));
        ushort4 h; h.x=f2bf(v[0]); h.y=f2bf(v[1]); h.z=f2bf(v[2]); h.w=f2bf(v[3]);
        *(ushort4*)(&xs[row * ROWP + c4 * 4]) = h;
    }
    __syncthreads();

    // pair0's x k-slices
    { const unsigned short* bp = xrow + ((ef >> 9) & 31) * 64 + q8;
      XA0 = *(const bf16x8*)(bp);      XA1 = *(const bf16x8*)(bp + 16);
      XA2 = *(const bf16x8*)(bp + 32); XA3 = *(const bf16x8*)(bp + 48); }

    #pragma unroll 1
    for (int s = 0; s < cnt; s += 2) {   // cnt even for every wave
        int e0 = gtab.ent[wv][s];
        int e1 = gtab.ent[wv][s + 1];
        int sn = (s + 2 < cnt) ? s + 2 : s + 1;
        int e2 = gtab.ent[wv][sn];       // last iter: dummy refetch, drained below
        PSTEP(e0, e1, WA0,WA1,WA2,WA3,WA4,WA5,WA6,WA7, XA0,XA1,XA2,XA3,
                      WB0,WB1,WB2,WB3,WB4,WB5,WB6,WB7, XB0,XB1,XB2,XB3);
        PSTEP(e1, e2, WB0,WB1,WB2,WB3,WB4,WB5,WB6,WB7, XB0,XB1,XB2,XB3,
                      WA0,WA1,WA2,WA3,WA4,WA5,WA6,WA7, XA0,XA1,XA2,XA3);
    }
    asm volatile("s_waitcnt vmcnt(0)");  // nothing in flight at s_endpgm

    atomicAdd(&t_red[bcol], tacc);
    __syncthreads();
    if (tid < BT) out[(size_t)btile * BT + tid] = t_red[tid];
}

extern "C" void kernel_launch(void* const* d_in, const int* in_sizes, int n_in,
                              void* d_out, int out_size, void* d_ws, size_t ws_size,
                              hipStream_t stream) {
    const float* x = (const float*)d_in[0];
    const float* W = (const float*)d_in[1];
    float* out = (float*)d_out;
    unsigned short* afrag = (unsigned short*)d_ws;   // 2.26 MB scratch
    wprep<<<P_NUM, 256, 0, stream>>>(W, afrag);
    fmfm_main<<<B_TOT / BT, NTH, 0, stream>>>(x, afrag, out);
}